// Round 10
// baseline (128.127 us; speedup 1.0000x reference)
//
#include <hip/hip_runtime.h>
#include <hip/hip_bf16.h>
#include <math.h>

#define N 8192
#define D 128
#define NC 10
#define FA 2732   // fill rows [0,FA) in k_gf
#define FB 5462   // fill rows [FA,FB) in k_self; [FB,N) in k_fuf

typedef float f4 __attribute__((ext_vector_type(4)));

__device__ __forceinline__ void nt_store4(float* p, float a, float b, float c, float d) {
    f4 v; v[0] = a; v[1] = b; v[2] = c; v[3] = d;
    __builtin_nontemporal_store(v, (f4*)p);
}

// ---------------- ws layout (bytes) ----------------
// 0       : u_idx  int[N]
// 32768   : labs   char[N]
// 40960   : nArr   float[N]
// 73728   : aArr   float[N]
// 106496  : dinv   float[N]
// 139264  : h      float[N*2]
// 204800  : gpre   float[N*2]
// 270336  : part1  float[64*33]
// 278784  : part2  float[32*20]
// 284160  : nuCnt  int
// 335872  : cpos   int[N]
// 524288  : gp     float[N*8]
// 2097152 : d2     float[cap*N]  (compacted squared distances, fast path)

__global__ void k_zero(int* __restrict__ p) {
    if (threadIdx.x == 0) *p = 0;
}

__global__ void k_prep(const float* __restrict__ x, const float* __restrict__ ohm,
                       const float* __restrict__ W, const float* __restrict__ bb,
                       char* __restrict__ labs, float* __restrict__ nArr,
                       float* __restrict__ h, int* __restrict__ u_idx,
                       int* __restrict__ cpos, int* __restrict__ nuCnt) {
    int gt = blockIdx.x * blockDim.x + threadIdx.x;
    int wid = gt >> 6;           // one wave per row
    int lane = gt & 63;
    if (wid >= N) return;
    const float2* xr = (const float2*)(x + (size_t)wid * D);
    float2 xv = xr[lane];
    float2 w0 = ((const float2*)W)[lane];
    float2 w1 = ((const float2*)(W + D))[lane];
    float nn = xv.x * xv.x + xv.y * xv.y;
    float h0 = xv.x * w0.x + xv.y * w0.y;
    float h1 = xv.x * w1.x + xv.y * w1.y;
    for (int off = 32; off; off >>= 1) {
        nn += __shfl_down(nn, off);
        h0 += __shfl_down(h0, off);
        h1 += __shfl_down(h1, off);
    }
    if (lane == 0) {
        nArr[wid] = nn;
        h[wid * 2 + 0] = h0 + bb[0];
        h[wid * 2 + 1] = h1 + bb[1];
        const float* orow = ohm + (size_t)wid * NC;
        int lab = -1;
        for (int c = 0; c < NC; ++c) {
            if (orow[c] > 0.5f) { lab = c; break; }
        }
        labs[wid] = (char)lab;
        if (lab < 0) {
            int slot = atomicAdd(nuCnt, 1);
            u_idx[slot] = wid;
            cpos[wid] = slot;
        }
    }
}

__global__ void k_sumA(const char* __restrict__ labs, const float* __restrict__ h,
                       float* __restrict__ part1) {
    __shared__ float L[256][33];
    int t = threadIdx.x;
    for (int s = 0; s < 33; ++s) L[t][s] = 0.f;
    int row = blockIdx.x * 256 + t;
    if (row < N) {
        int lab = labs[row];
        float h0 = h[row * 2], h1 = h[row * 2 + 1];
        if (lab >= 0) {
            L[t][lab * 2] = h0; L[t][lab * 2 + 1] = h1; L[t][22 + lab] = 1.f;
        } else {
            L[t][20] = h0; L[t][21] = h1; L[t][32] = 1.f;
        }
    }
    __syncthreads();
    if (t < 33) {
        float s = 0.f;
        for (int i = 0; i < 256; ++i) s += L[i][t];
        part1[blockIdx.x * 33 + t] = s;
    }
}

__device__ __forceinline__ void fill_row(const char* labs, float fc, int li,
                                         float* row, int t) {
#pragma unroll
    for (int s = 0; s < 8; ++s) {
        int c4 = t + 256 * s;
        char4 l4 = ((const char4*)labs)[c4];
        float o0 = (l4.x < 0) ? fc : ((l4.x == li) ? 1.f : 0.f);
        float o1 = (l4.y < 0) ? fc : ((l4.y == li) ? 1.f : 0.f);
        float o2 = (l4.z < 0) ? fc : ((l4.z == li) ? 1.f : 0.f);
        float o3 = (l4.w < 0) ? fc : ((l4.w == li) ? 1.f : 0.f);
        nt_store4(row + c4 * 4, o0, o1, o2, o3);
    }
}

// Heterogeneous: gy<12 -> D2 gemm tiles (BK=32, 18.3 KB LDS); gy>=12 -> fill rows < FA.
__global__ void k_gf(const float* __restrict__ x, const float* __restrict__ nArr,
                     const int* __restrict__ u_idx, const int* __restrict__ nuCnt,
                     int cap, const char* __restrict__ labs,
                     float* __restrict__ d2a, float* __restrict__ adj) {
    __shared__ float As[64][36];
    __shared__ float Bs[64][36];
    __shared__ int Ai[64];
    int nu = *nuCnt;
    int t = threadIdx.x;
    int gy = blockIdx.y;
    if (gy >= 12) {
        // -------- known-row fill, rows < FA --------
        if (nu > cap) return;                 // fallback: deferred
        int i = (gy - 12) * 128 + blockIdx.x;
        if (i >= FA) return;
        int li = labs[i];
        if (li < 0) return;
        float fc = 1.0f / fmaxf((float)nu, 1.0f);
        fill_row(labs, fc, li, adj + (size_t)i * N, t);
        return;
    }
    // -------- D2 gemm tile --------
    float* dst = (nu <= cap) ? d2a : adj;
    int j0 = blockIdx.x * 64;
    for (int yy = gy; yy * 64 < nu && yy < 128; yy += 12) {
        int a0 = yy * 64;
        if (yy != gy) __syncthreads();        // protect LDS reuse across yy
        int tx = t & 15, ty = t >> 4;
        float acc[4][4];
#pragma unroll
        for (int m = 0; m < 4; ++m)
#pragma unroll
            for (int q = 0; q < 4; ++q) acc[m][q] = 0.f;
        for (int kh = 0; kh < 4; ++kh) {
            if (kh) __syncthreads();          // protect LDS reuse across kh
            for (int c = t; c < 64 * 8; c += 256) {
                int r = c >> 3, cc = c & 7;
                int a = a0 + r;
                int orig = (a < nu) ? u_idx[a] : u_idx[0];
                if (kh == 0 && cc == 0) Ai[r] = (a < nu) ? orig : -1;
                float4 av = ((const float4*)(x + (size_t)orig * D + kh * 32))[cc];
                *(float4*)&As[r][cc * 4] = av;
                float4 bv = ((const float4*)(x + (size_t)(j0 + r) * D + kh * 32))[cc];
                *(float4*)&Bs[r][cc * 4] = bv;
            }
            __syncthreads();
#pragma unroll 4
            for (int k4 = 0; k4 < 8; ++k4) {
                float4 a4[4], b4[4];
#pragma unroll
                for (int m = 0; m < 4; ++m) a4[m] = *(const float4*)&As[ty + 16 * m][k4 * 4];
#pragma unroll
                for (int q = 0; q < 4; ++q) b4[q] = *(const float4*)&Bs[tx + 16 * q][k4 * 4];
#pragma unroll
                for (int m = 0; m < 4; ++m)
#pragma unroll
                    for (int q = 0; q < 4; ++q)
                        acc[m][q] += a4[m].x * b4[q].x + a4[m].y * b4[q].y
                                   + a4[m].z * b4[q].z + a4[m].w * b4[q].w;
            }
        }
#pragma unroll
        for (int m = 0; m < 4; ++m) {
            int ar = ty + 16 * m;
            int orig = Ai[ar];
            if (orig < 0) continue;
            float ni = nArr[orig];
#pragma unroll
            for (int q = 0; q < 4; ++q) {
                int j = j0 + tx + 16 * q;
                float v = fmaxf(ni + nArr[j] - 2.f * acc[m][q], 0.f);
                if (orig == j) v = 0.f;
                dst[(size_t)(a0 + ar) * N + j] = v;
            }
        }
    }
}

// Heterogeneous, LDS-light: blocks 0..1023 = select; 1024..2391 = fill rows [FA,FB).
__global__ void k_self(const float* __restrict__ d2a, const float* __restrict__ adj_ro,
                       const int* __restrict__ u_idx, const int* __restrict__ nuCnt,
                       int cap, const int* __restrict__ spars,
                       const char* __restrict__ labs,
                       float* __restrict__ aArr, float* __restrict__ dinv,
                       float* __restrict__ adj) {
    __shared__ float wsf[4];
    __shared__ int wsi[8];
    int nu = *nuCnt;
    int t = threadIdx.x;
    int bid = blockIdx.x;
    if (bid >= 1024) {
        // ---------------- known-row fill, rows [FA, FB) ----------------
        if (nu > cap) return;                    // fallback fills later
        float fc = 1.0f / fmaxf((float)nu, 1.0f);
        int fb = bid - 1024;
        for (int rr = 0; rr < 2; ++rr) {
            int i = FA + fb + 1368 * rr;
            if (i >= FB) break;
            int li = labs[i];
            if (li < 0) continue;
            fill_row(labs, fc, li, adj + (size_t)i * N, t);
        }
        return;
    }
    // ---------------- select ----------------
    const float* src = (nu <= cap) ? d2a : adj_ro;
    int k = *spars;
    int need = k + 1;
    int w = t >> 6;
    for (int rr = 0; rr < 8; ++rr) {
        int a = bid + 1024 * rr;
        if (a >= nu) break;                          // block-uniform
        const float4* rp = (const float4*)(src + (size_t)a * N);
        float v[32];
#pragma unroll
        for (int s = 0; s < 8; ++s) {
            float4 q = rp[t + 256 * s];
            v[s * 4 + 0] = q.x; v[s * 4 + 1] = q.y; v[s * 4 + 2] = q.z; v[s * 4 + 3] = q.w;
        }
        unsigned lo = 0u, hi = 0x7F800000u;
        for (int it = 0; it < 32; ++it) {
            unsigned mid = (lo + hi) >> 1;
            float mf = __uint_as_float(mid);
            int c = 0;
#pragma unroll
            for (int s = 0; s < 32; ++s) c += (v[s] <= mf) ? 1 : 0;
            for (int off = 32; off; off >>= 1) c += __shfl_down(c, off);
            if ((t & 63) == 0) wsi[(it & 1) * 4 + w] = c;
            __syncthreads();
            int base = (it & 1) * 4;
            c = wsi[base] + wsi[base + 1] + wsi[base + 2] + wsi[base + 3];
            if (lo < hi) {
                if (c >= need) hi = mid; else lo = mid + 1;
            }
        }
        float kvf = __uint_as_float(hi);
        float sum = 0.f; int clt = 0;
#pragma unroll
        for (int s = 0; s < 32; ++s) {
            if (v[s] < kvf) { clt++; sum += sqrtf(v[s]); }
        }
        for (int off = 32; off; off >>= 1) {
            sum += __shfl_down(sum, off);
            clt += __shfl_down(clt, off);
        }
        __syncthreads();
        if ((t & 63) == 0) { wsf[w] = sum; wsi[w] = clt; }
        __syncthreads();
        if (t == 0) {
            float sAll = wsf[0] + wsf[1] + wsf[2] + wsf[3];
            int cAll = wsi[0] + wsi[1] + wsi[2] + wsi[3];
            float skv = sqrtf(kvf);
            float aV = skv + 1e-10f;
            float b = sAll + (float)(k - cAll) * skv;
            float denom = aV * (float)k - b + 1e-10f;
            int orig = u_idx[a];
            aArr[orig] = aV;
            dinv[orig] = 1.0f / denom;
        }
        __syncthreads();
    }
}

// Heterogeneous: blocks 0..3071 = fu (adagae epilogue + partial adj.h);
//                blocks 3072..3754 = fill rows [FB, N). Fast path only for both.
__global__ void k_fuf(const float* __restrict__ d2a, const char* __restrict__ labs,
                      const int* __restrict__ u_idx, const float* __restrict__ aArr,
                      const float* __restrict__ dinv, const float* __restrict__ h,
                      const int* __restrict__ nuCnt, int cap,
                      float* __restrict__ adj, float* __restrict__ gp) {
    __shared__ float red[256];
    int nu = *nuCnt;
    if (nu > cap) return;
    int t = threadIdx.x;
    int bid = blockIdx.x;
    float fc = 1.0f / fmaxf((float)nu, 1.0f);
    if (bid >= 3072) {
        // ---------------- known-row fill, rows [FB, N) ----------------
        int fb = bid - 3072;
        for (int rr = 0; rr < 4; ++rr) {
            int i = FB + fb + 683 * rr;
            if (i >= N) break;
            int li = labs[i];
            if (li < 0) continue;
            fill_row(labs, fc, li, adj + (size_t)i * N, t);
        }
        return;
    }
    // ---------------- fu ----------------
    int jc = bid & 3;              // 0..3
    const float2* h2 = (const float2*)h;
    for (int a = (bid >> 2); a < nu; a += 768) {
        int i = u_idx[a];
        float ai = aArr[i], di = dinv[i];
        const float* drow = d2a + (size_t)a * N;
        float* orow = adj + (size_t)i * N;
        float s0 = 0.f, s1 = 0.f;
#pragma unroll
        for (int s = 0; s < 2; ++s) {
            int c4 = jc * 512 + s * 256 + t;
            int j = c4 * 4;
            float4 dv = ((const float4*)drow)[c4];
            char4 l4 = ((const char4*)labs)[c4];
            float dd[4] = {dv.x, dv.y, dv.z, dv.w};
            signed char ll[4] = {(signed char)l4.x, (signed char)l4.y,
                                 (signed char)l4.z, (signed char)l4.w};
            float v[4];
#pragma unroll
            for (int q = 0; q < 4; ++q) {
                if (ll[q] >= 0) {
                    v[q] = fc;
                } else {
                    float d = sqrtf(dd[q]);
                    v[q] = 0.5f * (fmaxf(ai - d, 0.f) * di
                                 + fmaxf(aArr[j + q] - d, 0.f) * dinv[j + q]);
                }
                float2 hh = h2[j + q];
                s0 += v[q] * hh.x;
                s1 += v[q] * hh.y;
            }
            nt_store4(orow + j, v[0], v[1], v[2], v[3]);
        }
        red[t] = s0; __syncthreads();
        for (int off = 128; off; off >>= 1) {
            if (t < off) red[t] += red[t + off];
            __syncthreads();
        }
        float r0 = red[0];
        __syncthreads();
        red[t] = s1; __syncthreads();
        for (int off = 128; off; off >>= 1) {
            if (t < off) red[t] += red[t + off];
            __syncthreads();
        }
        if (t == 0) { gp[a * 8 + jc * 2 + 0] = r0; gp[a * 8 + jc * 2 + 1] = red[0]; }
        __syncthreads();
    }
}

// FALLBACK (nu > cap): known-row fill (all rows) after select consumed adj scratch
__global__ void k_fill_known_fb(const char* __restrict__ labs,
                                const int* __restrict__ nuCnt, int cap,
                                float* __restrict__ adj) {
    int nu = *nuCnt;
    if (nu <= cap) return;
    int t = threadIdx.x;
    float fc = 1.0f / fmaxf((float)nu, 1.0f);
    for (int rr = 0; rr < 4; ++rr) {
        int i = blockIdx.x + 2048 * rr;
        int li = labs[i];
        if (li < 0) continue;
        fill_row(labs, fc, li, adj + (size_t)i * N, t);
    }
}

// FALLBACK: recompute distances tiled, final adj for unknown rows
__global__ void k_fu_slow(const float* __restrict__ x, const float* __restrict__ nArr,
                          const int* __restrict__ u_idx, const int* __restrict__ nuCnt,
                          int cap, const char* __restrict__ labs,
                          const float* __restrict__ aArr, const float* __restrict__ dinv,
                          float* __restrict__ adj) {
    __shared__ float As[64][D + 1];
    __shared__ float Bs[64][D + 1];
    __shared__ int Ai[64];
    int nu = *nuCnt;
    if (nu <= cap) return;
    int t = threadIdx.x;
    float fc = 1.0f / fmaxf((float)nu, 1.0f);
    int j0 = blockIdx.x * 64;
    for (int yy = blockIdx.y; yy * 64 < nu && yy < 128; yy += 12) {
        int a0 = yy * 64;
        if (yy != (int)blockIdx.y) __syncthreads();
        for (int c = t; c < 64 * 32; c += 256) {
            int r = c >> 5, c4 = c & 31;
            int a = a0 + r;
            int orig = (a < nu) ? u_idx[a] : u_idx[0];
            if (c4 == 0) Ai[r] = (a < nu) ? orig : -1;
            float4 av = ((const float4*)(x + (size_t)orig * D))[c4];
            As[r][c4 * 4 + 0] = av.x; As[r][c4 * 4 + 1] = av.y;
            As[r][c4 * 4 + 2] = av.z; As[r][c4 * 4 + 3] = av.w;
            float4 bv = ((const float4*)(x + (size_t)(j0 + r) * D))[c4];
            Bs[r][c4 * 4 + 0] = bv.x; Bs[r][c4 * 4 + 1] = bv.y;
            Bs[r][c4 * 4 + 2] = bv.z; Bs[r][c4 * 4 + 3] = bv.w;
        }
        __syncthreads();
        int tx = t & 15, ty = t >> 4;
        float acc[4][4];
#pragma unroll
        for (int m = 0; m < 4; ++m)
#pragma unroll
            for (int q = 0; q < 4; ++q) acc[m][q] = 0.f;
#pragma unroll 4
        for (int k = 0; k < D; ++k) {
            float a4[4], b4[4];
#pragma unroll
            for (int m = 0; m < 4; ++m) a4[m] = As[ty * 4 + m][k];
#pragma unroll
            for (int q = 0; q < 4; ++q) b4[q] = Bs[tx * 4 + q][k];
#pragma unroll
            for (int m = 0; m < 4; ++m)
#pragma unroll
                for (int q = 0; q < 4; ++q) acc[m][q] += a4[m] * b4[q];
        }
#pragma unroll
        for (int m = 0; m < 4; ++m) {
            int ar = ty * 4 + m;
            int orig = Ai[ar];
            if (orig < 0) continue;
            float ni = nArr[orig];
            float ai = aArr[orig], di = dinv[orig];
            int jb = j0 + tx * 4;
            float4 o;
            float* op = (float*)&o;
#pragma unroll
            for (int q = 0; q < 4; ++q) {
                int j = jb + q;
                int lj = labs[j];
                float v;
                if (lj >= 0) {
                    v = fc;
                } else {
                    float d2 = fmaxf(ni + nArr[j] - 2.f * acc[m][q], 0.f);
                    if (orig == j) d2 = 0.f;
                    float d = sqrtf(d2);
                    v = 0.5f * (fmaxf(ai - d, 0.f) * di + fmaxf(aArr[j] - d, 0.f) * dinv[j]);
                }
                op[q] = v;
            }
            *((float4*)(adj + (size_t)orig * N + jb)) = o;
        }
    }
}

// FALLBACK: g_pre for unknown rows = full adj_row . h
__global__ void k_gv(const float* __restrict__ adj, const float* __restrict__ h,
                     const int* __restrict__ u_idx, const int* __restrict__ nuCnt,
                     int cap, float* __restrict__ gpre) {
    __shared__ float red[256];
    int nu = *nuCnt;
    if (nu <= cap) return;
    int t = threadIdx.x;
    const float2* h2 = (const float2*)h;
    for (int rr = 0; rr < 8; ++rr) {
        int a = blockIdx.x + 1024 * rr;
        if (a >= nu) break;
        int orig = u_idx[a];
        const float4* row = (const float4*)(adj + (size_t)orig * N);
        float s0 = 0.f, s1 = 0.f;
#pragma unroll
        for (int s = 0; s < 8; ++s) {
            int c4 = t + 256 * s;
            float4 v = row[c4];
            int j = c4 * 4;
            float2 ha = h2[j + 0], hb = h2[j + 1], hc = h2[j + 2], hd = h2[j + 3];
            s0 += v.x * ha.x + v.y * hb.x + v.z * hc.x + v.w * hd.x;
            s1 += v.x * ha.y + v.y * hb.y + v.z * hc.y + v.w * hd.y;
        }
        red[t] = s0; __syncthreads();
        for (int off = 128; off; off >>= 1) {
            if (t < off) red[t] += red[t + off];
            __syncthreads();
        }
        if (t == 0) gpre[orig * 2 + 0] = red[0];
        __syncthreads();
        red[t] = s1; __syncthreads();
        for (int off = 128; off; off >>= 1) {
            if (t < off) red[t] += red[t + off];
            __syncthreads();
        }
        if (t == 0) gpre[orig * 2 + 1] = red[0];
        __syncthreads();
    }
}

// g = tanh(g_pre), outG, per-block label partial sums; reduces part1 in-block
__global__ void k_gagg(const char* __restrict__ labs, const float* __restrict__ gp,
                       const float* __restrict__ gpre, const int* __restrict__ cpos,
                       const int* __restrict__ nuCnt, int cap,
                       const float* __restrict__ part1, float* __restrict__ outg,
                       float* __restrict__ part2) {
    __shared__ float L[256][21];
    __shared__ float sc[33];
    int nu = *nuCnt;
    int t = threadIdx.x;
    for (int s = 0; s < 20; ++s) L[t][s] = 0.f;
    if (t < 33) {
        float s = 0.f;
        for (int i = 0; i < 64; ++i) s += part1[i * 33 + t];
        sc[t] = s;
    }
    __syncthreads();
    int i = blockIdx.x * 256 + t;
    int li = labs[i];
    float fc = 1.0f / fmaxf((float)nu, 1.0f);
    float g0, g1;
    if (li >= 0) {
        g0 = sc[li * 2 + 0] + fc * sc[20];
        g1 = sc[li * 2 + 1] + fc * sc[21];
    } else if (nu <= cap) {
        int a = cpos[i];
        g0 = gp[a * 8 + 0] + gp[a * 8 + 2] + gp[a * 8 + 4] + gp[a * 8 + 6];
        g1 = gp[a * 8 + 1] + gp[a * 8 + 3] + gp[a * 8 + 5] + gp[a * 8 + 7];
    } else {
        g0 = gpre[i * 2 + 0];
        g1 = gpre[i * 2 + 1];
    }
    g0 = tanhf(g0); g1 = tanhf(g1);
    outg[i * 2 + 0] = g0;
    outg[i * 2 + 1] = g1;
    if (li >= 0) { L[t][li * 2 + 0] = g0; L[t][li * 2 + 1] = g1; }
    __syncthreads();
    if (t < 20) {
        float s = 0.f;
        for (int r = 0; r < 256; ++r) s += L[r][t];
        part2[blockIdx.x * 20 + t] = s;
    }
}

// scores; centroid reduction inline
__global__ void k_scores(const float* __restrict__ g, const float* __restrict__ part2,
                         const float* __restrict__ part1, float* __restrict__ outs) {
    __shared__ float cent[20];
    int t = threadIdx.x;
    if (t < 20) {
        float s = 0.f;
        for (int i = 0; i < 32; ++i) s += part2[i * 20 + t];
        float cnt = 0.f;
        for (int i = 0; i < 64; ++i) cnt += part1[i * 33 + 22 + (t >> 1)];
        cent[t] = (cnt > 0.f) ? s / fmaxf(cnt, 1.0f) : 0.f;
    }
    __syncthreads();
    int i = blockIdx.x * 256 + t;
    float g0 = g[i * 2 + 0], g1 = g[i * 2 + 1];
#pragma unroll
    for (int c = 0; c < NC; ++c) {
        float d0 = g0 - cent[c * 2 + 0];
        float d1 = g1 - cent[c * 2 + 1];
        outs[i * NC + c] = -sqrtf(d0 * d0 + d1 * d1);
    }
}

extern "C" void kernel_launch(void* const* d_in, const int* in_sizes, int n_in,
                              void* d_out, int out_size, void* d_ws, size_t ws_size,
                              hipStream_t stream) {
    const float* x = (const float*)d_in[0];
    const float* ohm = (const float*)d_in[1];
    const float* W = (const float*)d_in[2];
    const float* b = (const float*)d_in[3];
    const int* spars = (const int*)d_in[4];

    float* out = (float*)d_out;
    float* outScores = out;                 // N*NC
    float* outG = out + (size_t)N * NC;     // N*2
    float* adj = outG + (size_t)N * 2;      // N*N

    char* wsb = (char*)d_ws;
    int* u_idx   = (int*)(wsb + 0);
    char* labs   = (char*)(wsb + 32768);
    float* nArr  = (float*)(wsb + 40960);
    float* aArr  = (float*)(wsb + 73728);
    float* dinv  = (float*)(wsb + 106496);
    float* hArr  = (float*)(wsb + 139264);
    float* gpre  = (float*)(wsb + 204800);
    float* part1 = (float*)(wsb + 270336);
    float* part2 = (float*)(wsb + 278784);
    int* nuCnt   = (int*)(wsb + 284160);
    int* cpos    = (int*)(wsb + 335872);
    float* gp    = (float*)(wsb + 524288);
    float* d2a   = (float*)(wsb + 2097152);

    long capL = ((long)ws_size - 2097152L) / ((long)N * 4);
    if (capL < 0) capL = 0;
    if (capL > N) capL = N;
    int cap = (int)capL;
    bool mayFallback = (cap < N);

    k_zero<<<1, 64, 0, stream>>>(nuCnt);
    k_prep<<<2048, 256, 0, stream>>>(x, ohm, W, b, labs, nArr, hArr, u_idx, cpos, nuCnt);
    k_sumA<<<64, 256, 0, stream>>>(labs, hArr, part1);
    k_gf<<<dim3(128, 34), 256, 0, stream>>>(x, nArr, u_idx, nuCnt, cap, labs, d2a, adj);
    k_self<<<2392, 256, 0, stream>>>(d2a, adj, u_idx, nuCnt, cap, spars, labs,
                                     aArr, dinv, adj);
    k_fuf<<<3755, 256, 0, stream>>>(d2a, labs, u_idx, aArr, dinv, hArr,
                                    nuCnt, cap, adj, gp);
    if (mayFallback) {
        k_fill_known_fb<<<2048, 256, 0, stream>>>(labs, nuCnt, cap, adj);
        k_fu_slow<<<dim3(128, 12), 256, 0, stream>>>(x, nArr, u_idx, nuCnt, cap, labs,
                                                     aArr, dinv, adj);
        k_gv<<<1024, 256, 0, stream>>>(adj, hArr, u_idx, nuCnt, cap, gpre);
    }
    k_gagg<<<32, 256, 0, stream>>>(labs, gp, gpre, cpos, nuCnt, cap, part1, outG, part2);
    k_scores<<<32, 256, 0, stream>>>(outG, part2, part1, outScores);
}

// Round 11
// 122.696 us; speedup vs baseline: 1.0443x; 1.0443x over previous
//
#include <hip/hip_runtime.h>
#include <hip/hip_bf16.h>
#include <math.h>

#define N 8192
#define D 128
#define NC 10
#define FSPLIT 2720   // rows filled inside k_gf; rest filled in k_self

typedef float f4 __attribute__((ext_vector_type(4)));

__device__ __forceinline__ void nt_store4(float* p, float a, float b, float c, float d) {
    f4 v; v[0] = a; v[1] = b; v[2] = c; v[3] = d;
    __builtin_nontemporal_store(v, (f4*)p);
}

// ---------------- ws layout (bytes) ----------------
// 0       : u_idx  int[N]
// 32768   : labs   char[N]
// 40960   : nArr   float[N]
// 73728   : aArr   float[N]
// 106496  : dinv   float[N]
// 139264  : h      float[N*2]
// 204800  : gpre   float[N*2]
// 270336  : part1  float[64*33]
// 278784  : part2  float[32*20]
// 284160  : nuCnt  int
// 335872  : cpos   int[N]
// 524288  : gp     float[N*8]
// 2097152 : d2     float[cap*N]  (compacted squared distances, fast path)

__global__ void k_zero(int* __restrict__ p) {
    if (threadIdx.x == 0) *p = 0;
}

__global__ void k_prep(const float* __restrict__ x, const float* __restrict__ ohm,
                       const float* __restrict__ W, const float* __restrict__ bb,
                       char* __restrict__ labs, float* __restrict__ nArr,
                       float* __restrict__ h, int* __restrict__ u_idx,
                       int* __restrict__ cpos, int* __restrict__ nuCnt) {
    int gt = blockIdx.x * blockDim.x + threadIdx.x;
    int wid = gt >> 6;           // one wave per row
    int lane = gt & 63;
    if (wid >= N) return;
    const float2* xr = (const float2*)(x + (size_t)wid * D);
    float2 xv = xr[lane];
    float2 w0 = ((const float2*)W)[lane];
    float2 w1 = ((const float2*)(W + D))[lane];
    float nn = xv.x * xv.x + xv.y * xv.y;
    float h0 = xv.x * w0.x + xv.y * w0.y;
    float h1 = xv.x * w1.x + xv.y * w1.y;
    for (int off = 32; off; off >>= 1) {
        nn += __shfl_down(nn, off);
        h0 += __shfl_down(h0, off);
        h1 += __shfl_down(h1, off);
    }
    if (lane == 0) {
        nArr[wid] = nn;
        h[wid * 2 + 0] = h0 + bb[0];
        h[wid * 2 + 1] = h1 + bb[1];
        const float* orow = ohm + (size_t)wid * NC;
        int lab = -1;
        for (int c = 0; c < NC; ++c) {
            if (orow[c] > 0.5f) { lab = c; break; }
        }
        labs[wid] = (char)lab;
        if (lab < 0) {
            int slot = atomicAdd(nuCnt, 1);
            u_idx[slot] = wid;
            cpos[wid] = slot;
        }
    }
}

__global__ void k_sumA(const char* __restrict__ labs, const float* __restrict__ h,
                       float* __restrict__ part1) {
    __shared__ float L[256][33];
    int t = threadIdx.x;
    for (int s = 0; s < 33; ++s) L[t][s] = 0.f;
    int row = blockIdx.x * 256 + t;
    if (row < N) {
        int lab = labs[row];
        float h0 = h[row * 2], h1 = h[row * 2 + 1];
        if (lab >= 0) {
            L[t][lab * 2] = h0; L[t][lab * 2 + 1] = h1; L[t][22 + lab] = 1.f;
        } else {
            L[t][20] = h0; L[t][21] = h1; L[t][32] = 1.f;
        }
    }
    __syncthreads();
    if (t < 33) {
        float s = 0.f;
        for (int i = 0; i < 256; ++i) s += L[i][t];
        part1[blockIdx.x * 33 + t] = s;
    }
}

__device__ __forceinline__ void fill_row(const char* labs, float fc, int li,
                                         float* row, int t) {
#pragma unroll
    for (int s = 0; s < 8; ++s) {
        int c4 = t + 256 * s;
        char4 l4 = ((const char4*)labs)[c4];
        float o0 = (l4.x < 0) ? fc : ((l4.x == li) ? 1.f : 0.f);
        float o1 = (l4.y < 0) ? fc : ((l4.y == li) ? 1.f : 0.f);
        float o2 = (l4.z < 0) ? fc : ((l4.z == li) ? 1.f : 0.f);
        float o3 = (l4.w < 0) ? fc : ((l4.w == li) ? 1.f : 0.f);
        nt_store4(row + c4 * 4, o0, o1, o2, o3);
    }
}

// Heterogeneous: gy<12 -> D2 gemm tiles (BK=32 chunks, 18.3 KB LDS -> 8 blocks/CU);
//                gy>=12 -> known-row fill for rows < FSPLIT (fast path only).
__global__ void k_gf(const float* __restrict__ x, const float* __restrict__ nArr,
                     const int* __restrict__ u_idx, const int* __restrict__ nuCnt,
                     int cap, const char* __restrict__ labs,
                     float* __restrict__ d2a, float* __restrict__ adj) {
    __shared__ float As[64][36];
    __shared__ float Bs[64][36];
    __shared__ int Ai[64];
    int nu = *nuCnt;
    int t = threadIdx.x;
    int gy = blockIdx.y;
    if (gy >= 12) {
        // -------- known-row fill, rows < FSPLIT --------
        if (nu > cap) return;                 // fallback: deferred (adj is D2 scratch)
        int i = (gy - 12) * 128 + blockIdx.x;
        if (i >= FSPLIT) return;
        int li = labs[i];
        if (li < 0) return;
        float fc = 1.0f / fmaxf((float)nu, 1.0f);
        fill_row(labs, fc, li, adj + (size_t)i * N, t);
        return;
    }
    // -------- D2 gemm tile --------
    float* dst = (nu <= cap) ? d2a : adj;
    int j0 = blockIdx.x * 64;
    for (int yy = gy; yy * 64 < nu && yy < 128; yy += 12) {
        int a0 = yy * 64;
        if (yy != gy) __syncthreads();        // protect LDS reuse across yy
        int tx = t & 15, ty = t >> 4;
        float acc[4][4];
#pragma unroll
        for (int m = 0; m < 4; ++m)
#pragma unroll
            for (int q = 0; q < 4; ++q) acc[m][q] = 0.f;
        for (int kh = 0; kh < 4; ++kh) {
            if (kh) __syncthreads();          // protect LDS reuse across kh
            for (int c = t; c < 64 * 8; c += 256) {
                int r = c >> 3, cc = c & 7;
                int a = a0 + r;
                int orig = (a < nu) ? u_idx[a] : u_idx[0];
                if (kh == 0 && cc == 0) Ai[r] = (a < nu) ? orig : -1;
                float4 av = ((const float4*)(x + (size_t)orig * D + kh * 32))[cc];
                *(float4*)&As[r][cc * 4] = av;
                float4 bv = ((const float4*)(x + (size_t)(j0 + r) * D + kh * 32))[cc];
                *(float4*)&Bs[r][cc * 4] = bv;
            }
            __syncthreads();
#pragma unroll 4
            for (int k4 = 0; k4 < 8; ++k4) {
                float4 a4[4], b4[4];
#pragma unroll
                for (int m = 0; m < 4; ++m) a4[m] = *(const float4*)&As[ty + 16 * m][k4 * 4];
#pragma unroll
                for (int q = 0; q < 4; ++q) b4[q] = *(const float4*)&Bs[tx + 16 * q][k4 * 4];
#pragma unroll
                for (int m = 0; m < 4; ++m)
#pragma unroll
                    for (int q = 0; q < 4; ++q)
                        acc[m][q] += a4[m].x * b4[q].x + a4[m].y * b4[q].y
                                   + a4[m].z * b4[q].z + a4[m].w * b4[q].w;
            }
        }
#pragma unroll
        for (int m = 0; m < 4; ++m) {
            int ar = ty + 16 * m;
            int orig = Ai[ar];
            if (orig < 0) continue;
            float ni = nArr[orig];
#pragma unroll
            for (int q = 0; q < 4; ++q) {
                int j = j0 + tx + 16 * q;
                float v = fmaxf(ni + nArr[j] - 2.f * acc[m][q], 0.f);
                if (orig == j) v = 0.f;
                dst[(size_t)(a0 + ar) * N + j] = v;
            }
        }
    }
}

// Heterogeneous, LDS-light: blocks 0..1023 = select; 1024..2391 = fill rows >= FSPLIT.
__global__ void k_self(const float* __restrict__ d2a, const float* __restrict__ adj_ro,
                       const int* __restrict__ u_idx, const int* __restrict__ nuCnt,
                       int cap, const int* __restrict__ spars,
                       const char* __restrict__ labs,
                       float* __restrict__ aArr, float* __restrict__ dinv,
                       float* __restrict__ adj) {
    __shared__ float wsf[4];
    __shared__ int wsi[8];
    int nu = *nuCnt;
    int t = threadIdx.x;
    int bid = blockIdx.x;
    if (bid >= 1024) {
        // ---------------- known-row fill, rows >= FSPLIT ----------------
        if (nu > cap) return;                    // fallback fills later (race-free)
        float fc = 1.0f / fmaxf((float)nu, 1.0f);
        int fb = bid - 1024;
        for (int rr = 0; rr < 4; ++rr) {
            int i = FSPLIT + fb + 1368 * rr;
            if (i >= N) break;
            int li = labs[i];
            if (li < 0) continue;
            fill_row(labs, fc, li, adj + (size_t)i * N, t);
        }
        return;
    }
    // ---------------- select ----------------
    const float* src = (nu <= cap) ? d2a : adj_ro;
    int k = *spars;
    int need = k + 1;
    int w = t >> 6;
    for (int rr = 0; rr < 8; ++rr) {
        int a = bid + 1024 * rr;
        if (a >= nu) break;                          // block-uniform
        const float4* rp = (const float4*)(src + (size_t)a * N);
        float v[32];
#pragma unroll
        for (int s = 0; s < 8; ++s) {
            float4 q = rp[t + 256 * s];
            v[s * 4 + 0] = q.x; v[s * 4 + 1] = q.y; v[s * 4 + 2] = q.z; v[s * 4 + 3] = q.w;
        }
        unsigned lo = 0u, hi = 0x7F800000u;
        for (int it = 0; it < 32; ++it) {
            unsigned mid = (lo + hi) >> 1;
            float mf = __uint_as_float(mid);
            int c = 0;
#pragma unroll
            for (int s = 0; s < 32; ++s) c += (v[s] <= mf) ? 1 : 0;
            for (int off = 32; off; off >>= 1) c += __shfl_down(c, off);
            if ((t & 63) == 0) wsi[(it & 1) * 4 + w] = c;
            __syncthreads();
            int base = (it & 1) * 4;
            c = wsi[base] + wsi[base + 1] + wsi[base + 2] + wsi[base + 3];
            if (lo < hi) {
                if (c >= need) hi = mid; else lo = mid + 1;
            }
        }
        float kvf = __uint_as_float(hi);
        float sum = 0.f; int clt = 0;
#pragma unroll
        for (int s = 0; s < 32; ++s) {
            if (v[s] < kvf) { clt++; sum += sqrtf(v[s]); }
        }
        for (int off = 32; off; off >>= 1) {
            sum += __shfl_down(sum, off);
            clt += __shfl_down(clt, off);
        }
        __syncthreads();
        if ((t & 63) == 0) { wsf[w] = sum; wsi[w] = clt; }
        __syncthreads();
        if (t == 0) {
            float sAll = wsf[0] + wsf[1] + wsf[2] + wsf[3];
            int cAll = wsi[0] + wsi[1] + wsi[2] + wsi[3];
            float skv = sqrtf(kvf);
            float aV = skv + 1e-10f;
            float b = sAll + (float)(k - cAll) * skv;
            float denom = aV * (float)k - b + 1e-10f;
            int orig = u_idx[a];
            aArr[orig] = aV;
            dinv[orig] = 1.0f / denom;
        }
        __syncthreads();
    }
}

// FAST path: unknown rows from stored D2, fused partial adj.h sums -> gp
__global__ void k_fu(const float* __restrict__ d2a, const char* __restrict__ labs,
                     const int* __restrict__ u_idx, const float* __restrict__ aArr,
                     const float* __restrict__ dinv, const float* __restrict__ h,
                     const int* __restrict__ nuCnt, int cap,
                     float* __restrict__ adj, float* __restrict__ gp) {
    __shared__ float red[256];
    int nu = *nuCnt;
    if (nu > cap) return;
    int t = threadIdx.x;
    int jc = blockIdx.x;           // 0..3
    float fc = 1.0f / fmaxf((float)nu, 1.0f);
    const float2* h2 = (const float2*)h;
    for (int a = blockIdx.y; a < nu; a += 768) {
        int i = u_idx[a];
        float ai = aArr[i], di = dinv[i];
        const float* drow = d2a + (size_t)a * N;
        float* orow = adj + (size_t)i * N;
        float s0 = 0.f, s1 = 0.f;
#pragma unroll
        for (int s = 0; s < 2; ++s) {
            int c4 = jc * 512 + s * 256 + t;
            int j = c4 * 4;
            float4 dv = ((const float4*)drow)[c4];
            char4 l4 = ((const char4*)labs)[c4];
            float dd[4] = {dv.x, dv.y, dv.z, dv.w};
            signed char ll[4] = {(signed char)l4.x, (signed char)l4.y,
                                 (signed char)l4.z, (signed char)l4.w};
            float v[4];
#pragma unroll
            for (int q = 0; q < 4; ++q) {
                if (ll[q] >= 0) {
                    v[q] = fc;
                } else {
                    float d = sqrtf(dd[q]);
                    v[q] = 0.5f * (fmaxf(ai - d, 0.f) * di
                                 + fmaxf(aArr[j + q] - d, 0.f) * dinv[j + q]);
                }
                float2 hh = h2[j + q];
                s0 += v[q] * hh.x;
                s1 += v[q] * hh.y;
            }
            nt_store4(orow + j, v[0], v[1], v[2], v[3]);
        }
        red[t] = s0; __syncthreads();
        for (int off = 128; off; off >>= 1) {
            if (t < off) red[t] += red[t + off];
            __syncthreads();
        }
        float r0 = red[0];
        __syncthreads();
        red[t] = s1; __syncthreads();
        for (int off = 128; off; off >>= 1) {
            if (t < off) red[t] += red[t + off];
            __syncthreads();
        }
        if (t == 0) { gp[a * 8 + jc * 2 + 0] = r0; gp[a * 8 + jc * 2 + 1] = red[0]; }
        __syncthreads();
    }
}

// FALLBACK (nu > cap): known-row fill (all rows) after select consumed adj scratch
__global__ void k_fill_known_fb(const char* __restrict__ labs,
                                const int* __restrict__ nuCnt, int cap,
                                float* __restrict__ adj) {
    int nu = *nuCnt;
    if (nu <= cap) return;
    int t = threadIdx.x;
    float fc = 1.0f / fmaxf((float)nu, 1.0f);
    for (int rr = 0; rr < 4; ++rr) {
        int i = blockIdx.x + 2048 * rr;
        int li = labs[i];
        if (li < 0) continue;
        fill_row(labs, fc, li, adj + (size_t)i * N, t);
    }
}

// FALLBACK: recompute distances tiled, final adj for unknown rows
__global__ void k_fu_slow(const float* __restrict__ x, const float* __restrict__ nArr,
                          const int* __restrict__ u_idx, const int* __restrict__ nuCnt,
                          int cap, const char* __restrict__ labs,
                          const float* __restrict__ aArr, const float* __restrict__ dinv,
                          float* __restrict__ adj) {
    __shared__ float As[64][D + 1];
    __shared__ float Bs[64][D + 1];
    __shared__ int Ai[64];
    int nu = *nuCnt;
    if (nu <= cap) return;
    int t = threadIdx.x;
    float fc = 1.0f / fmaxf((float)nu, 1.0f);
    int j0 = blockIdx.x * 64;
    for (int yy = blockIdx.y; yy * 64 < nu && yy < 128; yy += 12) {
        int a0 = yy * 64;
        if (yy != (int)blockIdx.y) __syncthreads();
        for (int c = t; c < 64 * 32; c += 256) {
            int r = c >> 5, c4 = c & 31;
            int a = a0 + r;
            int orig = (a < nu) ? u_idx[a] : u_idx[0];
            if (c4 == 0) Ai[r] = (a < nu) ? orig : -1;
            float4 av = ((const float4*)(x + (size_t)orig * D))[c4];
            As[r][c4 * 4 + 0] = av.x; As[r][c4 * 4 + 1] = av.y;
            As[r][c4 * 4 + 2] = av.z; As[r][c4 * 4 + 3] = av.w;
            float4 bv = ((const float4*)(x + (size_t)(j0 + r) * D))[c4];
            Bs[r][c4 * 4 + 0] = bv.x; Bs[r][c4 * 4 + 1] = bv.y;
            Bs[r][c4 * 4 + 2] = bv.z; Bs[r][c4 * 4 + 3] = bv.w;
        }
        __syncthreads();
        int tx = t & 15, ty = t >> 4;
        float acc[4][4];
#pragma unroll
        for (int m = 0; m < 4; ++m)
#pragma unroll
            for (int q = 0; q < 4; ++q) acc[m][q] = 0.f;
#pragma unroll 4
        for (int k = 0; k < D; ++k) {
            float a4[4], b4[4];
#pragma unroll
            for (int m = 0; m < 4; ++m) a4[m] = As[ty * 4 + m][k];
#pragma unroll
            for (int q = 0; q < 4; ++q) b4[q] = Bs[tx * 4 + q][k];
#pragma unroll
            for (int m = 0; m < 4; ++m)
#pragma unroll
                for (int q = 0; q < 4; ++q) acc[m][q] += a4[m] * b4[q];
        }
#pragma unroll
        for (int m = 0; m < 4; ++m) {
            int ar = ty * 4 + m;
            int orig = Ai[ar];
            if (orig < 0) continue;
            float ni = nArr[orig];
            float ai = aArr[orig], di = dinv[orig];
            int jb = j0 + tx * 4;
            float4 o;
            float* op = (float*)&o;
#pragma unroll
            for (int q = 0; q < 4; ++q) {
                int j = jb + q;
                int lj = labs[j];
                float v;
                if (lj >= 0) {
                    v = fc;
                } else {
                    float d2 = fmaxf(ni + nArr[j] - 2.f * acc[m][q], 0.f);
                    if (orig == j) d2 = 0.f;
                    float d = sqrtf(d2);
                    v = 0.5f * (fmaxf(ai - d, 0.f) * di + fmaxf(aArr[j] - d, 0.f) * dinv[j]);
                }
                op[q] = v;
            }
            *((float4*)(adj + (size_t)orig * N + jb)) = o;
        }
    }
}

// FALLBACK: g_pre for unknown rows = full adj_row . h
__global__ void k_gv(const float* __restrict__ adj, const float* __restrict__ h,
                     const int* __restrict__ u_idx, const int* __restrict__ nuCnt,
                     int cap, float* __restrict__ gpre) {
    __shared__ float red[256];
    int nu = *nuCnt;
    if (nu <= cap) return;
    int t = threadIdx.x;
    const float2* h2 = (const float2*)h;
    for (int rr = 0; rr < 8; ++rr) {
        int a = blockIdx.x + 1024 * rr;
        if (a >= nu) break;
        int orig = u_idx[a];
        const float4* row = (const float4*)(adj + (size_t)orig * N);
        float s0 = 0.f, s1 = 0.f;
#pragma unroll
        for (int s = 0; s < 8; ++s) {
            int c4 = t + 256 * s;
            float4 v = row[c4];
            int j = c4 * 4;
            float2 ha = h2[j + 0], hb = h2[j + 1], hc = h2[j + 2], hd = h2[j + 3];
            s0 += v.x * ha.x + v.y * hb.x + v.z * hc.x + v.w * hd.x;
            s1 += v.x * ha.y + v.y * hb.y + v.z * hc.y + v.w * hd.y;
        }
        red[t] = s0; __syncthreads();
        for (int off = 128; off; off >>= 1) {
            if (t < off) red[t] += red[t + off];
            __syncthreads();
        }
        if (t == 0) gpre[orig * 2 + 0] = red[0];
        __syncthreads();
        red[t] = s1; __syncthreads();
        for (int off = 128; off; off >>= 1) {
            if (t < off) red[t] += red[t + off];
            __syncthreads();
        }
        if (t == 0) gpre[orig * 2 + 1] = red[0];
        __syncthreads();
    }
}

// g = tanh(g_pre), outG, per-block label partial sums; reduces part1 in-block
__global__ void k_gagg(const char* __restrict__ labs, const float* __restrict__ gp,
                       const float* __restrict__ gpre, const int* __restrict__ cpos,
                       const int* __restrict__ nuCnt, int cap,
                       const float* __restrict__ part1, float* __restrict__ outg,
                       float* __restrict__ part2) {
    __shared__ float L[256][21];
    __shared__ float sc[33];
    int nu = *nuCnt;
    int t = threadIdx.x;
    for (int s = 0; s < 20; ++s) L[t][s] = 0.f;
    if (t < 33) {
        float s = 0.f;
        for (int i = 0; i < 64; ++i) s += part1[i * 33 + t];
        sc[t] = s;
    }
    __syncthreads();
    int i = blockIdx.x * 256 + t;
    int li = labs[i];
    float fc = 1.0f / fmaxf((float)nu, 1.0f);
    float g0, g1;
    if (li >= 0) {
        g0 = sc[li * 2 + 0] + fc * sc[20];
        g1 = sc[li * 2 + 1] + fc * sc[21];
    } else if (nu <= cap) {
        int a = cpos[i];
        g0 = gp[a * 8 + 0] + gp[a * 8 + 2] + gp[a * 8 + 4] + gp[a * 8 + 6];
        g1 = gp[a * 8 + 1] + gp[a * 8 + 3] + gp[a * 8 + 5] + gp[a * 8 + 7];
    } else {
        g0 = gpre[i * 2 + 0];
        g1 = gpre[i * 2 + 1];
    }
    g0 = tanhf(g0); g1 = tanhf(g1);
    outg[i * 2 + 0] = g0;
    outg[i * 2 + 1] = g1;
    if (li >= 0) { L[t][li * 2 + 0] = g0; L[t][li * 2 + 1] = g1; }
    __syncthreads();
    if (t < 20) {
        float s = 0.f;
        for (int r = 0; r < 256; ++r) s += L[r][t];
        part2[blockIdx.x * 20 + t] = s;
    }
}

// scores; centroid reduction inline
__global__ void k_scores(const float* __restrict__ g, const float* __restrict__ part2,
                         const float* __restrict__ part1, float* __restrict__ outs) {
    __shared__ float cent[20];
    int t = threadIdx.x;
    if (t < 20) {
        float s = 0.f;
        for (int i = 0; i < 32; ++i) s += part2[i * 20 + t];
        float cnt = 0.f;
        for (int i = 0; i < 64; ++i) cnt += part1[i * 33 + 22 + (t >> 1)];
        cent[t] = (cnt > 0.f) ? s / fmaxf(cnt, 1.0f) : 0.f;
    }
    __syncthreads();
    int i = blockIdx.x * 256 + t;
    float g0 = g[i * 2 + 0], g1 = g[i * 2 + 1];
#pragma unroll
    for (int c = 0; c < NC; ++c) {
        float d0 = g0 - cent[c * 2 + 0];
        float d1 = g1 - cent[c * 2 + 1];
        outs[i * NC + c] = -sqrtf(d0 * d0 + d1 * d1);
    }
}

extern "C" void kernel_launch(void* const* d_in, const int* in_sizes, int n_in,
                              void* d_out, int out_size, void* d_ws, size_t ws_size,
                              hipStream_t stream) {
    const float* x = (const float*)d_in[0];
    const float* ohm = (const float*)d_in[1];
    const float* W = (const float*)d_in[2];
    const float* b = (const float*)d_in[3];
    const int* spars = (const int*)d_in[4];

    float* out = (float*)d_out;
    float* outScores = out;                 // N*NC
    float* outG = out + (size_t)N * NC;     // N*2
    float* adj = outG + (size_t)N * 2;      // N*N

    char* wsb = (char*)d_ws;
    int* u_idx   = (int*)(wsb + 0);
    char* labs   = (char*)(wsb + 32768);
    float* nArr  = (float*)(wsb + 40960);
    float* aArr  = (float*)(wsb + 73728);
    float* dinv  = (float*)(wsb + 106496);
    float* hArr  = (float*)(wsb + 139264);
    float* gpre  = (float*)(wsb + 204800);
    float* part1 = (float*)(wsb + 270336);
    float* part2 = (float*)(wsb + 278784);
    int* nuCnt   = (int*)(wsb + 284160);
    int* cpos    = (int*)(wsb + 335872);
    float* gp    = (float*)(wsb + 524288);
    float* d2a   = (float*)(wsb + 2097152);

    long capL = ((long)ws_size - 2097152L) / ((long)N * 4);
    if (capL < 0) capL = 0;
    if (capL > N) capL = N;
    int cap = (int)capL;
    bool mayFallback = (cap < N);

    k_zero<<<1, 64, 0, stream>>>(nuCnt);
    k_prep<<<2048, 256, 0, stream>>>(x, ohm, W, b, labs, nArr, hArr, u_idx, cpos, nuCnt);
    k_sumA<<<64, 256, 0, stream>>>(labs, hArr, part1);
    k_gf<<<dim3(128, 34), 256, 0, stream>>>(x, nArr, u_idx, nuCnt, cap, labs, d2a, adj);
    k_self<<<2392, 256, 0, stream>>>(d2a, adj, u_idx, nuCnt, cap, spars, labs,
                                     aArr, dinv, adj);
    k_fu<<<dim3(4, 768), 256, 0, stream>>>(d2a, labs, u_idx, aArr, dinv, hArr,
                                           nuCnt, cap, adj, gp);
    if (mayFallback) {
        k_fill_known_fb<<<2048, 256, 0, stream>>>(labs, nuCnt, cap, adj);
        k_fu_slow<<<dim3(128, 12), 256, 0, stream>>>(x, nArr, u_idx, nuCnt, cap, labs,
                                                     aArr, dinv, adj);
        k_gv<<<1024, 256, 0, stream>>>(adj, hArr, u_idx, nuCnt, cap, gpre);
    }
    k_gagg<<<32, 256, 0, stream>>>(labs, gp, gpre, cpos, nuCnt, cap, part1, outG, part2);
    k_scores<<<32, 256, 0, stream>>>(outG, part2, part1, outScores);
}